// Round 1
// baseline (213.335 us; speedup 1.0000x reference)
//
#include <hip/hip_runtime.h>
#include <math.h>

#define D 1024
#define NROWS 16384
#define NBUF 512
#define NBLK_A 512

// ws layout (float indices)
#define OFF_INVSTDX 0
#define OFF_INVSTDY 1024
#define OFF_CONST   2048   // tau_in, tau_out, a_in, a_out
#define OFF_KEY     2056   // unsigned long long (8B aligned: 2056*4=8224)
#define OFF_RES     2058   // idx(int), valid(int), boost(f), damp(f)
#define OFF_GATE    2064   // 16384 floats
#define OFF_MEAN    18448  // 1024 floats
#define OFF_PART    19472  // NBLK_A * 1024 floats

__device__ __forceinline__ float4 ld4(const float* p) { return *(const float4*)p; }

__device__ __forceinline__ float wave_red(float v) {
    #pragma unroll
    for (int off = 32; off > 0; off >>= 1) v += __shfl_xor(v, off, 64);
    return v;
}

__device__ __forceinline__ float gelu_f(float x) {
    // 0.5*x*(1+tanh(0.79788456*(x+0.044715*x^3))); tanh(u)=1-2/(1+exp(2u)) (stable)
    float u = 0.7978845608028654f * (x + 0.044715f * x * x * x);
    float e = __expf(2.0f * u);
    float t = 1.0f - 2.0f / (e + 1.0f);
    return 0.5f * x * (1.0f + t);
}

// ---------------- K0: precompute inv_std, constants, init key -----------------
__global__ void k_init(const float* __restrict__ ema_x, const float* __restrict__ ema_x2,
                       const float* __restrict__ ema_y, const float* __restrict__ ema_y2,
                       const float* __restrict__ lti, const float* __restrict__ lto,
                       const float* __restrict__ lai, const float* __restrict__ lao,
                       float* __restrict__ ws) {
    int t = threadIdx.x;
    if (t < D) {
        float vx = ema_x2[t] - ema_x[t] * ema_x[t]; vx = vx > 0.f ? vx : 0.f;
        ws[OFF_INVSTDX + t] = 1.0f / (sqrtf(vx) + 1e-5f);
        float vy = ema_y2[t] - ema_y[t] * ema_y[t]; vy = vy > 0.f ? vy : 0.f;
        ws[OFF_INVSTDY + t] = 1.0f / (sqrtf(vy) + 1e-5f);
    }
    if (t == 0) {
        ws[OFF_CONST + 0] = expf(lti[0]);
        ws[OFF_CONST + 1] = expf(lto[0]);
        ws[OFF_CONST + 2] = 1.0f / (1.0f + expf(-lai[0]));
        ws[OFF_CONST + 3] = 1.0f / (1.0f + expf(-lao[0]));
        *(unsigned long long*)&ws[OFF_KEY] = 0ull;
    }
}

// ---------------- K1: pass A — gate per row + column partial sums -------------
__global__ __launch_bounds__(256) void k_passA(const float* __restrict__ x,
                                               const float* __restrict__ ema_x,
                                               const float* __restrict__ ema_y,
                                               float* __restrict__ ws) {
    __shared__ float s_acc[D];
    const int tid = threadIdx.x;
    const int wave = tid >> 6, lane = tid & 63;
    for (int i = tid; i < D; i += 256) s_acc[i] = 0.0f;
    __syncthreads();

    const float tau_in = ws[OFF_CONST + 0], tau_out = ws[OFF_CONST + 1];
    const float a_in  = ws[OFF_CONST + 2], a_out  = ws[OFF_CONST + 3];

    int col[4];
    float4 emx[4], isx[4], emy[4], isy[4];
    #pragma unroll
    for (int j = 0; j < 4; ++j) {
        col[j] = 4 * lane + 256 * j;
        emx[j] = ld4(&ema_x[col[j]]);
        isx[j] = ld4(&ws[OFF_INVSTDX + col[j]]);
        emy[j] = ld4(&ema_y[col[j]]);
        isy[j] = ld4(&ws[OFF_INVSTDY + col[j]]);
    }
    float4 acc[4];
    #pragma unroll
    for (int j = 0; j < 4; ++j) acc[j] = make_float4(0.f, 0.f, 0.f, 0.f);

    const int gw = blockIdx.x * 4 + wave;      // 0..2047
    const int r0 = gw * 8;                     // 8 rows per wave
    for (int r = r0; r < r0 + 8; ++r) {
        const float* xr = x + (size_t)r * D;
        float4 yv[4];
        float zin = 0.f, zout = 0.f;
        #pragma unroll
        for (int j = 0; j < 4; ++j) {
            float4 xv = ld4(&xr[col[j]]);
            float dx, dy;
            dx = (xv.x - emx[j].x) * isx[j].x; zin += dx * dx;
            dx = (xv.y - emx[j].y) * isx[j].y; zin += dx * dx;
            dx = (xv.z - emx[j].z) * isx[j].z; zin += dx * dx;
            dx = (xv.w - emx[j].w) * isx[j].w; zin += dx * dx;
            yv[j].x = gelu_f(xv.x); dy = (yv[j].x - emy[j].x) * isy[j].x; zout += dy * dy;
            yv[j].y = gelu_f(xv.y); dy = (yv[j].y - emy[j].y) * isy[j].y; zout += dy * dy;
            yv[j].z = gelu_f(xv.z); dy = (yv[j].z - emy[j].z) * isy[j].z; zout += dy * dy;
            yv[j].w = gelu_f(xv.w); dy = (yv[j].w - emy[j].w) * isy[j].w; zout += dy * dy;
        }
        zin  = wave_red(zin)  * (1.0f / D);
        zout = wave_red(zout) * (1.0f / D);
        float g = ((1.0f - a_in)  + a_in  * __expf(-tau_in  * zin)) *
                  ((1.0f - a_out) + a_out * __expf(-tau_out * zout));
        if (lane == 0) ws[OFF_GATE + r] = g;
        #pragma unroll
        for (int j = 0; j < 4; ++j) {
            acc[j].x += yv[j].x * g;
            acc[j].y += yv[j].y * g;
            acc[j].z += yv[j].z * g;
            acc[j].w += yv[j].w * g;
        }
    }
    #pragma unroll
    for (int j = 0; j < 4; ++j) {
        atomicAdd(&s_acc[col[j] + 0], acc[j].x);
        atomicAdd(&s_acc[col[j] + 1], acc[j].y);
        atomicAdd(&s_acc[col[j] + 2], acc[j].z);
        atomicAdd(&s_acc[col[j] + 3], acc[j].w);
    }
    __syncthreads();
    // 256 threads write 1024 partials coalesced
    float4 pv = *(float4*)&s_acc[tid * 4];
    *(float4*)&ws[OFF_PART + (size_t)blockIdx.x * D + tid * 4] = pv;
}

// ---------------- K2: reduce partials -> y1_mean ------------------------------
__global__ void k_mean(float* __restrict__ ws) {
    int d = blockIdx.x * 128 + threadIdx.x;   // 8 blocks x 128
    float s = 0.f;
    const float* p = &ws[OFF_PART];
    for (int b = 0; b < NBLK_A; ++b) s += p[(size_t)b * D + d];
    ws[OFF_MEAN + d] = s * (1.0f / (float)NROWS);
}

// ---------------- K3: sims over buf + argmax via atomicMax key ----------------
__global__ __launch_bounds__(256) void k_sims(const float* __restrict__ buf,
                                              const unsigned char* __restrict__ mask,
                                              float* __restrict__ ws) {
    __shared__ float s_red[4];
    __shared__ float s_inv;
    const int tid = threadIdx.x, wave = tid >> 6, lane = tid & 63;

    // norm of y1_mean (each block computes it; 4KB, cached)
    float4 mv = ld4(&ws[OFF_MEAN + tid * 4]);
    float ns = mv.x * mv.x + mv.y * mv.y + mv.z * mv.z + mv.w * mv.w;
    ns = wave_red(ns);
    if (lane == 0) s_red[wave] = ns;
    __syncthreads();
    if (tid == 0) {
        float t = s_red[0] + s_red[1] + s_red[2] + s_red[3];
        s_inv = 1.0f / fmaxf(sqrtf(t), 1e-12f);
    }
    __syncthreads();
    const float inv = s_inv;

    int col[4];
    float4 mvv[4];
    #pragma unroll
    for (int j = 0; j < 4; ++j) {
        col[j] = 4 * lane + 256 * j;
        mvv[j] = ld4(&ws[OFF_MEAN + col[j]]);
    }
    unsigned long long* keyp = (unsigned long long*)&ws[OFF_KEY];
    const int gw = blockIdx.x * 4 + wave;     // 0..63, 8 buf rows each
    for (int n = gw * 8; n < gw * 8 + 8; ++n) {
        const float* br = buf + (size_t)n * D;
        float dot = 0.f, bns = 0.f;
        #pragma unroll
        for (int j = 0; j < 4; ++j) {
            float4 bv = ld4(&br[col[j]]);
            dot += bv.x * mvv[j].x + bv.y * mvv[j].y + bv.z * mvv[j].z + bv.w * mvv[j].w;
            bns += bv.x * bv.x + bv.y * bv.y + bv.z * bv.z + bv.w * bv.w;
        }
        dot = wave_red(dot);
        bns = wave_red(bns);
        if (lane == 0) {
            float sim = -1.0f;
            if (mask[n]) sim = (dot * inv) / fmaxf(sqrtf(bns), 1e-12f);
            unsigned int fb = __float_as_uint(sim);
            unsigned int mono = (fb & 0x80000000u) ? ~fb : (fb | 0x80000000u);
            // ~n in low bits => ties resolve to smallest index (jnp.argmax semantics)
            unsigned long long key = ((unsigned long long)mono << 32) | (unsigned int)(~n);
            atomicMax(keyp, key);
        }
    }
}

// ---------------- K4: decode winner, compute boost/damp/valid -----------------
__global__ __launch_bounds__(1024) void k_final(const float* __restrict__ buf,
                                                const float* __restrict__ facil,
                                                const float* __restrict__ lkb,
                                                const float* __restrict__ lkd,
                                                float* __restrict__ ws) {
    __shared__ float s_sum[16];
    __shared__ int s_fin;
    const int tid = threadIdx.x, wave = tid >> 6, lane = tid & 63;
    if (tid == 0) s_fin = 1;
    __syncthreads();

    unsigned long long key = *(const unsigned long long*)&ws[OFF_KEY];
    int idx = (int)(~(unsigned int)(key & 0xFFFFFFFFull));
    unsigned int mono = (unsigned int)(key >> 32);
    unsigned int fb = (mono & 0x80000000u) ? (mono ^ 0x80000000u) : ~mono;
    float sim = __uint_as_float(fb);

    float v = buf[(size_t)idx * D + tid];
    if (!isfinite(v)) atomicAnd(&s_fin, 0);
    float ns = wave_red(v * v);
    if (lane == 0) s_sum[wave] = ns;
    __syncthreads();
    if (tid == 0) {
        float t = 0.f;
        #pragma unroll
        for (int i = 0; i < 16; ++i) t += s_sum[i];
        float nrm = sqrtf(t);
        int valid = s_fin && (nrm >= 1e-6f);
        float sim_val = fminf(fmaxf(sim, 0.0f), 1.0f);
        float fl = facil[idx] * ((sim_val > 0.88f) ? 2.0f : 1.0f);
        float mod = (fl - 1.0f) * sim_val;
        float kb = fminf(fmaxf(expf(lkb[0]), 0.01f), 4.0f);
        float kd = fminf(fmaxf(expf(lkd[0]), 0.01f), 0.9f);
        float boost = 1.0f + kb * mod;
        float damp = fmaxf(0.01f, 1.0f - kd * mod);
        int* wi = (int*)ws;
        wi[OFF_RES + 0] = idx;
        wi[OFF_RES + 1] = valid;
        ws[OFF_RES + 2] = boost;
        ws[OFF_RES + 3] = damp;
    }
}

// ---------------- K5: pass B — recompute y1, project on v, write out ----------
__global__ __launch_bounds__(256) void k_passB(const float* __restrict__ x,
                                               const float* __restrict__ buf,
                                               const float* __restrict__ ws,
                                               float* __restrict__ out) {
    const int tid = threadIdx.x, wave = tid >> 6, lane = tid & 63;
    const int* wi = (const int*)ws;
    const int idx = wi[OFF_RES + 0];
    const int valid = wi[OFF_RES + 1];
    const float boost = ws[OFF_RES + 2], damp = ws[OFF_RES + 3];
    const float dampe = valid ? damp : 1.0f;
    const float coef = valid ? (boost - damp) : 0.0f;

    int col[4];
    float4 vv[4];
    const float* vrow = buf + (size_t)idx * D;
    #pragma unroll
    for (int j = 0; j < 4; ++j) {
        col[j] = 4 * lane + 256 * j;
        vv[j] = ld4(&vrow[col[j]]);
        if (!valid) vv[j] = make_float4(0.f, 0.f, 0.f, 0.f);  // avoid NaN*0
    }

    const int gw = blockIdx.x * 4 + wave;
    const int r0 = gw * 8;
    for (int r = r0; r < r0 + 8; ++r) {
        const float* xr = x + (size_t)r * D;
        const float g = ws[OFF_GATE + r];
        float4 y1[4];
        float proj = 0.f;
        #pragma unroll
        for (int j = 0; j < 4; ++j) {
            float4 xv = ld4(&xr[col[j]]);
            y1[j].x = gelu_f(xv.x) * g; proj += y1[j].x * vv[j].x;
            y1[j].y = gelu_f(xv.y) * g; proj += y1[j].y * vv[j].y;
            y1[j].z = gelu_f(xv.z) * g; proj += y1[j].z * vv[j].z;
            y1[j].w = gelu_f(xv.w) * g; proj += y1[j].w * vv[j].w;
        }
        proj = wave_red(proj);
        const float pc = proj * coef;
        float* orow = out + (size_t)r * D;
        #pragma unroll
        for (int j = 0; j < 4; ++j) {
            float4 o;
            o.x = y1[j].x * dampe + pc * vv[j].x;
            o.y = y1[j].y * dampe + pc * vv[j].y;
            o.z = y1[j].z * dampe + pc * vv[j].z;
            o.w = y1[j].w * dampe + pc * vv[j].w;
            *(float4*)&orow[col[j]] = o;
        }
    }
}

extern "C" void kernel_launch(void* const* d_in, const int* in_sizes, int n_in,
                              void* d_out, int out_size, void* d_ws, size_t ws_size,
                              hipStream_t stream) {
    const float* x      = (const float*)d_in[0];
    const float* lti    = (const float*)d_in[1];
    const float* lto    = (const float*)d_in[2];
    const float* lai    = (const float*)d_in[3];
    const float* lao    = (const float*)d_in[4];
    const float* lkb    = (const float*)d_in[5];
    const float* lkd    = (const float*)d_in[6];
    const float* ema_x  = (const float*)d_in[7];
    const float* ema_x2 = (const float*)d_in[8];
    const float* ema_y  = (const float*)d_in[9];
    const float* ema_y2 = (const float*)d_in[10];
    const float* buf    = (const float*)d_in[11];
    const float* facil  = (const float*)d_in[12];
    const unsigned char* mask = (const unsigned char*)d_in[13];
    float* ws  = (float*)d_ws;
    float* out = (float*)d_out;

    hipLaunchKernelGGL(k_init,  dim3(1),   dim3(1024), 0, stream,
                       ema_x, ema_x2, ema_y, ema_y2, lti, lto, lai, lao, ws);
    hipLaunchKernelGGL(k_passA, dim3(NBLK_A), dim3(256), 0, stream, x, ema_x, ema_y, ws);
    hipLaunchKernelGGL(k_mean,  dim3(8),   dim3(128),  0, stream, ws);
    hipLaunchKernelGGL(k_sims,  dim3(16),  dim3(256),  0, stream, buf, mask, ws);
    hipLaunchKernelGGL(k_final, dim3(1),   dim3(1024), 0, stream, buf, facil, lkb, lkd, ws);
    hipLaunchKernelGGL(k_passB, dim3(NBLK_A), dim3(256), 0, stream, x, buf, ws, out);
}

// Round 3
// 196.580 us; speedup vs baseline: 1.0852x; 1.0852x over previous
//
#include <hip/hip_runtime.h>
#include <math.h>

#define D 1024
#define NROWS 16384
#define NBUF 512

// ws layout (float indices)
#define OFF_MEAN 0      // 1024 floats: atomically accumulated column sums of y1
#define OFF_KEY  1024   // unsigned long long (byte 4096, 8B aligned)
#define OFF_RES  1026   // idx(int), valid(int), boost(f), damp(f)
#define OFF_GATE 1032   // 16384 floats
#define ZERO_BYTES 4112 // covers MEAN + KEY (+ pad)

typedef float nfloat4 __attribute__((ext_vector_type(4)));

__device__ __forceinline__ float4 ld4(const float* p) { return *(const float4*)p; }
__device__ __forceinline__ void st4_nt(float* p, float4 v) {
    nfloat4 nv = { v.x, v.y, v.z, v.w };
    __builtin_nontemporal_store(nv, (nfloat4*)p);
}

__device__ __forceinline__ float wave_red(float v) {
    #pragma unroll
    for (int off = 32; off > 0; off >>= 1) v += __shfl_xor(v, off, 64);
    return v;
}

__device__ __forceinline__ float gelu_f(float x) {
    // 0.5*x*(1+tanh(0.79788456*(x+0.044715*x^3))); tanh(u)=1-2/(1+exp(2u)) (stable)
    float u = 0.7978845608028654f * (x + 0.044715f * x * x * x);
    float e = __expf(2.0f * u);
    float t = 1.0f - 2.0f / (e + 1.0f);
    return 0.5f * x * (1.0f + t);
}

__device__ __forceinline__ float4 inv_std4(float4 m, float4 m2) {
    float4 r;
    r.x = 1.0f / (sqrtf(fmaxf(m2.x - m.x * m.x, 0.f)) + 1e-5f);
    r.y = 1.0f / (sqrtf(fmaxf(m2.y - m.y * m.y, 0.f)) + 1e-5f);
    r.z = 1.0f / (sqrtf(fmaxf(m2.z - m.z * m.z, 0.f)) + 1e-5f);
    r.w = 1.0f / (sqrtf(fmaxf(m2.w - m.w * m.w, 0.f)) + 1e-5f);
    return r;
}

// ---------------- K1: pass A — gate per row + global column sums --------------
// grid 1024 x 256; 4 waves/block, 4 rows/wave => 16 waves/CU resident.
__global__ __launch_bounds__(256, 4) void k_passA(const float* __restrict__ x,
                                                  const float* __restrict__ ema_x,
                                                  const float* __restrict__ ema_x2,
                                                  const float* __restrict__ ema_y,
                                                  const float* __restrict__ ema_y2,
                                                  const float* __restrict__ lti,
                                                  const float* __restrict__ lto,
                                                  const float* __restrict__ lai,
                                                  const float* __restrict__ lao,
                                                  float* __restrict__ ws) {
    __shared__ float s_acc[D];
    const int tid = threadIdx.x;
    const int wave = tid >> 6, lane = tid & 63;
    for (int i = tid; i < D; i += 256) s_acc[i] = 0.0f;
    __syncthreads();

    const float tau_in = __expf(lti[0]), tau_out = __expf(lto[0]);
    const float a_in  = 1.0f / (1.0f + __expf(-lai[0]));
    const float a_out = 1.0f / (1.0f + __expf(-lao[0]));

    int col[4];
    float4 emx[4], isx[4], emy[4], isy[4];
    #pragma unroll
    for (int j = 0; j < 4; ++j) {
        col[j] = 4 * lane + 256 * j;
        emx[j] = ld4(&ema_x[col[j]]);
        isx[j] = inv_std4(emx[j], ld4(&ema_x2[col[j]]));
        emy[j] = ld4(&ema_y[col[j]]);
        isy[j] = inv_std4(emy[j], ld4(&ema_y2[col[j]]));
    }
    float4 acc[4];
    #pragma unroll
    for (int j = 0; j < 4; ++j) acc[j] = make_float4(0.f, 0.f, 0.f, 0.f);

    const int r0 = (blockIdx.x * 4 + wave) * 4;   // 4 rows per wave
    for (int r = r0; r < r0 + 4; ++r) {
        const float* xr = x + (size_t)r * D;
        float4 yv[4];
        float zin = 0.f, zout = 0.f;
        #pragma unroll
        for (int j = 0; j < 4; ++j) {
            float4 xv = ld4(&xr[col[j]]);
            float dx, dy;
            dx = (xv.x - emx[j].x) * isx[j].x; zin += dx * dx;
            dx = (xv.y - emx[j].y) * isx[j].y; zin += dx * dx;
            dx = (xv.z - emx[j].z) * isx[j].z; zin += dx * dx;
            dx = (xv.w - emx[j].w) * isx[j].w; zin += dx * dx;
            yv[j].x = gelu_f(xv.x); dy = (yv[j].x - emy[j].x) * isy[j].x; zout += dy * dy;
            yv[j].y = gelu_f(xv.y); dy = (yv[j].y - emy[j].y) * isy[j].y; zout += dy * dy;
            yv[j].z = gelu_f(xv.z); dy = (yv[j].z - emy[j].z) * isy[j].z; zout += dy * dy;
            yv[j].w = gelu_f(xv.w); dy = (yv[j].w - emy[j].w) * isy[j].w; zout += dy * dy;
        }
        zin  = wave_red(zin)  * (1.0f / D);
        zout = wave_red(zout) * (1.0f / D);
        float g = ((1.0f - a_in)  + a_in  * __expf(-tau_in  * zin)) *
                  ((1.0f - a_out) + a_out * __expf(-tau_out * zout));
        if (lane == 0) ws[OFF_GATE + r] = g;
        #pragma unroll
        for (int j = 0; j < 4; ++j) {
            acc[j].x += yv[j].x * g;
            acc[j].y += yv[j].y * g;
            acc[j].z += yv[j].z * g;
            acc[j].w += yv[j].w * g;
        }
    }
    #pragma unroll
    for (int j = 0; j < 4; ++j) {
        atomicAdd(&s_acc[col[j] + 0], acc[j].x);
        atomicAdd(&s_acc[col[j] + 1], acc[j].y);
        atomicAdd(&s_acc[col[j] + 2], acc[j].z);
        atomicAdd(&s_acc[col[j] + 3], acc[j].w);
    }
    __syncthreads();
    // one global atomic per column per block (1024 blocks -> 1024 adds/address)
    for (int i = tid; i < D; i += 256) atomicAdd(&ws[OFF_MEAN + i], s_acc[i]);
}

// ---------------- K2: sims over buf + argmax via atomicMax key ----------------
// Note: ws[OFF_MEAN] holds the SUM of y1 columns; the 1/NROWS factor cancels
// in the normalization (m_n = sum/||sum||), so no separate mean kernel.
__global__ __launch_bounds__(256) void k_sims(const float* __restrict__ buf,
                                              const unsigned char* __restrict__ mask,
                                              float* __restrict__ ws) {
    __shared__ float s_red[4];
    __shared__ float s_inv;
    const int tid = threadIdx.x, wave = tid >> 6, lane = tid & 63;

    float4 mv = ld4(&ws[OFF_MEAN + tid * 4]);
    float ns = mv.x * mv.x + mv.y * mv.y + mv.z * mv.z + mv.w * mv.w;
    ns = wave_red(ns);
    if (lane == 0) s_red[wave] = ns;
    __syncthreads();
    if (tid == 0) {
        float t = s_red[0] + s_red[1] + s_red[2] + s_red[3];
        s_inv = 1.0f / fmaxf(sqrtf(t), 1e-12f);
    }
    __syncthreads();
    const float inv = s_inv;

    int col[4];
    float4 mvv[4];
    #pragma unroll
    for (int j = 0; j < 4; ++j) {
        col[j] = 4 * lane + 256 * j;
        mvv[j] = ld4(&ws[OFF_MEAN + col[j]]);
    }
    unsigned long long* keyp = (unsigned long long*)&ws[OFF_KEY];
    const int n0 = (blockIdx.x * 4 + wave) * 4;   // 32 blocks x 4 waves x 4 rows
    for (int n = n0; n < n0 + 4; ++n) {
        const float* br = buf + (size_t)n * D;
        float dot = 0.f, bns = 0.f;
        #pragma unroll
        for (int j = 0; j < 4; ++j) {
            float4 bv = ld4(&br[col[j]]);
            dot += bv.x * mvv[j].x + bv.y * mvv[j].y + bv.z * mvv[j].z + bv.w * mvv[j].w;
            bns += bv.x * bv.x + bv.y * bv.y + bv.z * bv.z + bv.w * bv.w;
        }
        dot = wave_red(dot);
        bns = wave_red(bns);
        if (lane == 0) {
            float sim = -1.0f;
            if (mask[n]) sim = (dot * inv) / fmaxf(sqrtf(bns), 1e-12f);
            unsigned int fb = __float_as_uint(sim);
            unsigned int mono = (fb & 0x80000000u) ? ~fb : (fb | 0x80000000u);
            // ~n in low bits => ties resolve to smallest index (jnp.argmax semantics)
            unsigned long long key = ((unsigned long long)mono << 32) | (unsigned int)(~n);
            atomicMax(keyp, key);
        }
    }
}

// ---------------- K3: decode winner, compute boost/damp/valid -----------------
__global__ __launch_bounds__(1024) void k_final(const float* __restrict__ buf,
                                                const float* __restrict__ facil,
                                                const float* __restrict__ lkb,
                                                const float* __restrict__ lkd,
                                                float* __restrict__ ws) {
    __shared__ float s_sum[16];
    __shared__ int s_fin;
    const int tid = threadIdx.x, wave = tid >> 6, lane = tid & 63;
    if (tid == 0) s_fin = 1;
    __syncthreads();

    unsigned long long key = *(const unsigned long long*)&ws[OFF_KEY];
    int idx = (int)(~(unsigned int)(key & 0xFFFFFFFFull));
    unsigned int mono = (unsigned int)(key >> 32);
    unsigned int fb = (mono & 0x80000000u) ? (mono ^ 0x80000000u) : ~mono;
    float sim = __uint_as_float(fb);

    float v = buf[(size_t)idx * D + tid];
    if (!isfinite(v)) atomicAnd(&s_fin, 0);
    float ns = wave_red(v * v);
    if (lane == 0) s_sum[wave] = ns;
    __syncthreads();
    if (tid == 0) {
        float t = 0.f;
        #pragma unroll
        for (int i = 0; i < 16; ++i) t += s_sum[i];
        float nrm = sqrtf(t);
        int valid = s_fin && (nrm >= 1e-6f);
        float sim_val = fminf(fmaxf(sim, 0.0f), 1.0f);
        float fl = facil[idx] * ((sim_val > 0.88f) ? 2.0f : 1.0f);
        float mod = (fl - 1.0f) * sim_val;
        float kb = fminf(fmaxf(expf(lkb[0]), 0.01f), 4.0f);
        float kd = fminf(fmaxf(expf(lkd[0]), 0.01f), 0.9f);
        float boost = 1.0f + kb * mod;
        float damp = fmaxf(0.01f, 1.0f - kd * mod);
        int* wi = (int*)ws;
        wi[OFF_RES + 0] = idx;
        wi[OFF_RES + 1] = valid;
        ws[OFF_RES + 2] = boost;
        ws[OFF_RES + 3] = damp;
    }
}

// ---------------- K4: pass B — recompute y1, project on v, write out ----------
__global__ __launch_bounds__(256, 4) void k_passB(const float* __restrict__ x,
                                                  const float* __restrict__ buf,
                                                  const float* __restrict__ ws,
                                                  float* __restrict__ out) {
    const int tid = threadIdx.x, wave = tid >> 6, lane = tid & 63;
    const int* wi = (const int*)ws;
    const int idx = wi[OFF_RES + 0];
    const int valid = wi[OFF_RES + 1];
    const float boost = ws[OFF_RES + 2], damp = ws[OFF_RES + 3];
    const float dampe = valid ? damp : 1.0f;
    const float coef = valid ? (boost - damp) : 0.0f;

    int col[4];
    float4 vv[4];
    const float* vrow = buf + (size_t)idx * D;
    #pragma unroll
    for (int j = 0; j < 4; ++j) {
        col[j] = 4 * lane + 256 * j;
        vv[j] = ld4(&vrow[col[j]]);
        if (!valid) vv[j] = make_float4(0.f, 0.f, 0.f, 0.f);  // avoid NaN*0
    }

    const int r0 = (blockIdx.x * 4 + wave) * 4;
    for (int r = r0; r < r0 + 4; ++r) {
        const float* xr = x + (size_t)r * D;
        const float g = ws[OFF_GATE + r];
        float4 y1[4];
        float proj = 0.f;
        #pragma unroll
        for (int j = 0; j < 4; ++j) {
            float4 xv = ld4(&xr[col[j]]);
            y1[j].x = gelu_f(xv.x) * g; proj += y1[j].x * vv[j].x;
            y1[j].y = gelu_f(xv.y) * g; proj += y1[j].y * vv[j].y;
            y1[j].z = gelu_f(xv.z) * g; proj += y1[j].z * vv[j].z;
            y1[j].w = gelu_f(xv.w) * g; proj += y1[j].w * vv[j].w;
        }
        proj = wave_red(proj);
        const float pc = proj * coef;
        float* orow = out + (size_t)r * D;
        #pragma unroll
        for (int j = 0; j < 4; ++j) {
            float4 o;
            o.x = y1[j].x * dampe + pc * vv[j].x;
            o.y = y1[j].y * dampe + pc * vv[j].y;
            o.z = y1[j].z * dampe + pc * vv[j].z;
            o.w = y1[j].w * dampe + pc * vv[j].w;
            st4_nt(&orow[col[j]], o);
        }
    }
}

extern "C" void kernel_launch(void* const* d_in, const int* in_sizes, int n_in,
                              void* d_out, int out_size, void* d_ws, size_t ws_size,
                              hipStream_t stream) {
    const float* x      = (const float*)d_in[0];
    const float* lti    = (const float*)d_in[1];
    const float* lto    = (const float*)d_in[2];
    const float* lai    = (const float*)d_in[3];
    const float* lao    = (const float*)d_in[4];
    const float* lkb    = (const float*)d_in[5];
    const float* lkd    = (const float*)d_in[6];
    const float* ema_x  = (const float*)d_in[7];
    const float* ema_x2 = (const float*)d_in[8];
    const float* ema_y  = (const float*)d_in[9];
    const float* ema_y2 = (const float*)d_in[10];
    const float* buf    = (const float*)d_in[11];
    const float* facil  = (const float*)d_in[12];
    const unsigned char* mask = (const unsigned char*)d_in[13];
    float* ws  = (float*)d_ws;
    float* out = (float*)d_out;

    (void)hipMemsetAsync(d_ws, 0, ZERO_BYTES, stream);
    hipLaunchKernelGGL(k_passA, dim3(1024), dim3(256), 0, stream,
                       x, ema_x, ema_x2, ema_y, ema_y2, lti, lto, lai, lao, ws);
    hipLaunchKernelGGL(k_sims,  dim3(32),  dim3(256), 0, stream, buf, mask, ws);
    hipLaunchKernelGGL(k_final, dim3(1),   dim3(1024), 0, stream, buf, facil, lkb, lkd, ws);
    hipLaunchKernelGGL(k_passB, dim3(1024), dim3(256), 0, stream, x, buf, ws, out);
}